// Round 1
// baseline (1745.217 us; speedup 1.0000x reference)
//
#include <hip/hip_runtime.h>

#define TT 128
#define NB 64
#define NSZ 32
#define MSZ 8
#define PSZ 16
#define LD 36
#define LDK 20

__device__ __forceinline__ void fma4(float4& a, float s, const float4 v){
  a.x = fmaf(s, v.x, a.x);
  a.y = fmaf(s, v.y, a.y);
  a.z = fmaf(s, v.z, a.z);
  a.w = fmaf(s, v.w, a.w);
}
__device__ __forceinline__ void fma2(float2& a, float s, const float2 v){
  a.x = fmaf(s, v.x, a.x);
  a.y = fmaf(s, v.y, a.y);
}

// ---------------- Forward Kalman filter: 1 block per batch ----------------
__global__ __launch_bounds__(256) void kf_forward(
    const float* __restrict__ Yg, const float* __restrict__ Ug,
    const float* __restrict__ Ag, const float* __restrict__ Bg,
    const float* __restrict__ Cg, const float* __restrict__ mu0g,
    const float* __restrict__ Sig0g,
    float* __restrict__ outg, float* __restrict__ wsSig, float* __restrict__ wsMu)
{
  const int b = blockIdx.x;
  const int tid = threadIdx.x;
  const int i32 = tid >> 3;
  const int j4 = (tid & 7) << 2;
  const int i16 = tid >> 4;
  const int j2 = (tid & 15) << 1;
  const int sj = tid & 15;

  __shared__ __align__(16) float Sig[NSZ][LD];
  __shared__ __align__(16) float Amat[NSZ][LD];
  __shared__ __align__(16) float ATs[NSZ][LD];
  __shared__ __align__(16) float T1[NSZ][LD];
  __shared__ __align__(16) float Sigp[NSZ][LD];
  __shared__ __align__(16) float IKC[NSZ][LD];
  __shared__ __align__(16) float IKCT[NSZ][LD];
  __shared__ __align__(16) float Cmat[PSZ][LD];
  __shared__ __align__(16) float CS[PSZ][LD];
  __shared__ __align__(16) float Kt[PSZ][LD];
  __shared__ __align__(16) float CT[NSZ][LDK];
  __shared__ __align__(16) float Kmat[NSZ][LDK];
  __shared__ float Lch[PSZ][17];
  __shared__ float Sraw[PSZ][17];
  __shared__ float rdiag[PSZ];
  __shared__ float Bv[NSZ][MSZ];
  __shared__ float yv[PSZ], uv[MSZ], muv[NSZ], mupv[NSZ], rvv[PSZ], mufv[NSZ];

  const size_t bt0 = (size_t)b * TT;

  for (int e = tid; e < NSZ*NSZ; e += 256) Sig[e >> 5][e & 31] = Sig0g[e];
  if (tid < NSZ) muv[tid] = mu0g[tid];

  {
    float4 a4 = *(const float4*)(Ag + bt0*(NSZ*NSZ) + tid*4);
    float bb = Bg[bt0*(NSZ*MSZ) + tid];
    float2 c2 = *(const float2*)(Cg + bt0*(PSZ*NSZ) + tid*2);
    Amat[i32][j4+0]=a4.x; Amat[i32][j4+1]=a4.y; Amat[i32][j4+2]=a4.z; Amat[i32][j4+3]=a4.w;
    ATs[j4+0][i32]=a4.x; ATs[j4+1][i32]=a4.y; ATs[j4+2][i32]=a4.z; ATs[j4+3][i32]=a4.w;
    Bv[tid>>3][tid&7] = bb;
    const int ci = tid >> 4, cj = (tid & 15) << 1;
    Cmat[ci][cj]=c2.x; Cmat[ci][cj+1]=c2.y;
    CT[cj][ci]=c2.x; CT[cj+1][ci]=c2.y;
    if (tid < PSZ) yv[tid] = Yg[bt0*PSZ + tid];
    if (tid < MSZ) uv[tid] = Ug[bt0*MSZ + tid];
  }
  __syncthreads();

  for (int t = 0; t < TT; ++t) {
    const size_t bt = bt0 + t;
    // prefetch next step's inputs into registers
    float4 na4 = make_float4(0.f,0.f,0.f,0.f);
    float2 nc2 = make_float2(0.f,0.f);
    float nbb = 0.f, nyy = 0.f, nuu = 0.f;
    if (t + 1 < TT) {
      na4 = *(const float4*)(Ag + (bt+1)*(NSZ*NSZ) + tid*4);
      nbb = Bg[(bt+1)*(NSZ*MSZ) + tid];
      nc2 = *(const float2*)(Cg + (bt+1)*(PSZ*NSZ) + tid*2);
      if (tid < PSZ) nyy = Yg[(bt+1)*PSZ + tid];
      if (tid < MSZ) nuu = Ug[(bt+1)*MSZ + tid];
    }

    // Phase A: T1 = A*Sig ; mu_p = A*mu + B*u
    {
      float4 acc = make_float4(0.f,0.f,0.f,0.f);
      #pragma unroll
      for (int k0 = 0; k0 < NSZ; k0 += 4) {
        float4 a = *(const float4*)&Amat[i32][k0];
        fma4(acc, a.x, *(const float4*)&Sig[k0+0][j4]);
        fma4(acc, a.y, *(const float4*)&Sig[k0+1][j4]);
        fma4(acc, a.z, *(const float4*)&Sig[k0+2][j4]);
        fma4(acc, a.w, *(const float4*)&Sig[k0+3][j4]);
      }
      *(float4*)&T1[i32][j4] = acc;
      if (tid < NSZ) {
        float m = 0.f;
        #pragma unroll
        for (int k = 0; k < NSZ; ++k) m = fmaf(Amat[tid][k], muv[k], m);
        #pragma unroll
        for (int k = 0; k < MSZ; ++k) m = fmaf(Bv[tid][k], uv[k], m);
        mupv[tid] = m;
      }
    }
    __syncthreads();

    // Phase B: Sig_p = T1*A^T + Q ; store Sig_p, mu_p to workspace
    {
      float4 acc = make_float4(0.f,0.f,0.f,0.f);
      #pragma unroll
      for (int k0 = 0; k0 < NSZ; k0 += 4) {
        float4 a = *(const float4*)&T1[i32][k0];
        fma4(acc, a.x, *(const float4*)&ATs[k0+0][j4]);
        fma4(acc, a.y, *(const float4*)&ATs[k0+1][j4]);
        fma4(acc, a.z, *(const float4*)&ATs[k0+2][j4]);
        fma4(acc, a.w, *(const float4*)&ATs[k0+3][j4]);
      }
      acc.x += (i32 == j4+0) ? 0.01f : 0.f;
      acc.y += (i32 == j4+1) ? 0.01f : 0.f;
      acc.z += (i32 == j4+2) ? 0.01f : 0.f;
      acc.w += (i32 == j4+3) ? 0.01f : 0.f;
      *(float4*)&Sigp[i32][j4] = acc;
      *(float4*)(wsSig + (bt*NSZ + i32)*NSZ + j4) = acc;
      if (tid < NSZ) wsMu[bt*NSZ + tid] = mupv[tid];
    }
    __syncthreads();

    // Phase C: CS = C*Sig_p (16x32) ; r = y - C*mu_p
    {
      float2 acc = make_float2(0.f,0.f);
      #pragma unroll
      for (int k0 = 0; k0 < NSZ; k0 += 4) {
        float4 c4 = *(const float4*)&Cmat[i16][k0];
        fma2(acc, c4.x, *(const float2*)&Sigp[k0+0][j2]);
        fma2(acc, c4.y, *(const float2*)&Sigp[k0+1][j2]);
        fma2(acc, c4.z, *(const float2*)&Sigp[k0+2][j2]);
        fma2(acc, c4.w, *(const float2*)&Sigp[k0+3][j2]);
      }
      *(float2*)&CS[i16][j2] = acc;
      if (tid < PSZ) {
        float r = yv[tid];
        #pragma unroll
        for (int k = 0; k < NSZ; ++k) r = fmaf(-Cmat[tid][k], mupv[k], r);
        rvv[tid] = r;
      }
    }
    __syncthreads();

    // Phase D: Sraw = CS*C^T + R (16x16)
    {
      float acc = 0.f;
      #pragma unroll
      for (int k0 = 0; k0 < NSZ; k0 += 4) {
        float4 cs4 = *(const float4*)&CS[i16][k0];
        acc = fmaf(cs4.x, CT[k0+0][sj], acc);
        acc = fmaf(cs4.y, CT[k0+1][sj], acc);
        acc = fmaf(cs4.z, CT[k0+2][sj], acc);
        acc = fmaf(cs4.w, CT[k0+3][sj], acc);
      }
      Sraw[i16][sj] = acc + ((i16 == sj) ? 0.01f : 0.f);
    }
    __syncthreads();

    // Phase E: Cholesky of sym(Sraw), single wave, shuffle-based
    if (tid < 64) {
      const int j = tid & 15;
      float col[16];
      #pragma unroll
      for (int i = 0; i < 16; ++i) col[i] = 0.5f*(Sraw[i][j] + Sraw[j][i]);
      #pragma unroll
      for (int k = 0; k < 16; ++k) {
        float ck[16];
        #pragma unroll
        for (int i = 0; i < 16; ++i) { if (i >= k) ck[i] = __shfl(col[i], k); else ck[i] = 0.f; }
        float d = sqrtf(ck[k]);
        float rd = 1.0f / d;
        if (j == k) {
          #pragma unroll
          for (int i = 0; i < 16; ++i) { if (i >= k) col[i] = ck[i]*rd; }
        } else if (j > k) {
          float ljk = ck[j]*rd;
          #pragma unroll
          for (int i = 0; i < 16; ++i) { if (i > k) col[i] = fmaf(-(ck[i]*rd), ljk, col[i]); }
        }
      }
      if (tid < 16) {
        #pragma unroll
        for (int i = 0; i < 16; ++i) { if (i >= j) Lch[i][j] = col[i]; }
        rdiag[j] = 1.0f / col[j];
      }
    }
    __syncthreads();

    // Phase G: solve S * Kt = CS  (32 RHS columns)
    if (tid < 32) {
      float x[16];
      #pragma unroll
      for (int i = 0; i < 16; ++i) {
        float acc = CS[i][tid];
        #pragma unroll
        for (int m = 0; m < 16; ++m) { if (m < i) acc = fmaf(-Lch[i][m], x[m], acc); }
        x[i] = acc * rdiag[i];
      }
      #pragma unroll
      for (int i = 15; i >= 0; --i) {
        float acc = x[i];
        #pragma unroll
        for (int m = 0; m < 16; ++m) { if (m > i) acc = fmaf(-Lch[m][i], x[m], acc); }
        x[i] = acc * rdiag[i];
        Kt[i][tid] = x[i];
        Kmat[tid][i] = x[i];
      }
    }
    __syncthreads();

    // Phase H: IKC = I - K*C ; mu_f = mu_p + K*r
    {
      float4 acc = make_float4(0.f,0.f,0.f,0.f);
      #pragma unroll
      for (int p0 = 0; p0 < PSZ; p0 += 4) {
        float4 k4 = *(const float4*)&Kmat[i32][p0];
        fma4(acc, -k4.x, *(const float4*)&Cmat[p0+0][j4]);
        fma4(acc, -k4.y, *(const float4*)&Cmat[p0+1][j4]);
        fma4(acc, -k4.z, *(const float4*)&Cmat[p0+2][j4]);
        fma4(acc, -k4.w, *(const float4*)&Cmat[p0+3][j4]);
      }
      acc.x += (i32 == j4+0) ? 1.f : 0.f;
      acc.y += (i32 == j4+1) ? 1.f : 0.f;
      acc.z += (i32 == j4+2) ? 1.f : 0.f;
      acc.w += (i32 == j4+3) ? 1.f : 0.f;
      *(float4*)&IKC[i32][j4] = acc;
      IKCT[j4+0][i32]=acc.x; IKCT[j4+1][i32]=acc.y; IKCT[j4+2][i32]=acc.z; IKCT[j4+3][i32]=acc.w;
      if (tid < NSZ) {
        float m = mupv[tid];
        #pragma unroll
        for (int p0 = 0; p0 < PSZ; p0 += 4) {
          float4 k4 = *(const float4*)&Kmat[tid][p0];
          m = fmaf(k4.x, rvv[p0+0], m);
          m = fmaf(k4.y, rvv[p0+1], m);
          m = fmaf(k4.z, rvv[p0+2], m);
          m = fmaf(k4.w, rvv[p0+3], m);
        }
        mufv[tid] = m;
      }
    }
    __syncthreads();

    // Phase I: T2 = IKC * Sig_p  (into T1)
    {
      float4 acc = make_float4(0.f,0.f,0.f,0.f);
      #pragma unroll
      for (int k0 = 0; k0 < NSZ; k0 += 4) {
        float4 w4 = *(const float4*)&IKC[i32][k0];
        fma4(acc, w4.x, *(const float4*)&Sigp[k0+0][j4]);
        fma4(acc, w4.y, *(const float4*)&Sigp[k0+1][j4]);
        fma4(acc, w4.z, *(const float4*)&Sigp[k0+2][j4]);
        fma4(acc, w4.w, *(const float4*)&Sigp[k0+3][j4]);
      }
      *(float4*)&T1[i32][j4] = acc;
    }
    __syncthreads();

    // Phase J: G = T2*IKC^T + 0.01*K*K^T  (into IKC)
    {
      float4 acc = make_float4(0.f,0.f,0.f,0.f);
      #pragma unroll
      for (int k0 = 0; k0 < NSZ; k0 += 4) {
        float4 t4 = *(const float4*)&T1[i32][k0];
        fma4(acc, t4.x, *(const float4*)&IKCT[k0+0][j4]);
        fma4(acc, t4.y, *(const float4*)&IKCT[k0+1][j4]);
        fma4(acc, t4.z, *(const float4*)&IKCT[k0+2][j4]);
        fma4(acc, t4.w, *(const float4*)&IKCT[k0+3][j4]);
      }
      float4 acc2 = make_float4(0.f,0.f,0.f,0.f);
      #pragma unroll
      for (int p0 = 0; p0 < PSZ; p0 += 4) {
        float4 k4 = *(const float4*)&Kmat[i32][p0];
        fma4(acc2, k4.x, *(const float4*)&Kt[p0+0][j4]);
        fma4(acc2, k4.y, *(const float4*)&Kt[p0+1][j4]);
        fma4(acc2, k4.z, *(const float4*)&Kt[p0+2][j4]);
        fma4(acc2, k4.w, *(const float4*)&Kt[p0+3][j4]);
      }
      acc.x = fmaf(0.01f, acc2.x, acc.x);
      acc.y = fmaf(0.01f, acc2.y, acc.y);
      acc.z = fmaf(0.01f, acc2.z, acc.z);
      acc.w = fmaf(0.01f, acc2.w, acc.w);
      *(float4*)&IKC[i32][j4] = acc;
    }
    __syncthreads();

    // Phase K: Sig_f = sym(G) ; outputs ; stage next inputs
    {
      float4 sf;
      sf.x = 0.5f*(IKC[i32][j4+0] + IKC[j4+0][i32]);
      sf.y = 0.5f*(IKC[i32][j4+1] + IKC[j4+1][i32]);
      sf.z = 0.5f*(IKC[i32][j4+2] + IKC[j4+2][i32]);
      sf.w = 0.5f*(IKC[i32][j4+3] + IKC[j4+3][i32]);
      *(float4*)&Sig[i32][j4] = sf;
      float* op = outg + (bt*NSZ + i32)*(NSZ+1) + 1 + j4;
      op[0]=sf.x; op[1]=sf.y; op[2]=sf.z; op[3]=sf.w;
      if (tid < NSZ) {
        muv[tid] = mufv[tid];
        outg[(bt*NSZ + tid)*(NSZ+1)] = mufv[tid];
      }
      if (t + 1 < TT) {
        Amat[i32][j4+0]=na4.x; Amat[i32][j4+1]=na4.y; Amat[i32][j4+2]=na4.z; Amat[i32][j4+3]=na4.w;
        ATs[j4+0][i32]=na4.x; ATs[j4+1][i32]=na4.y; ATs[j4+2][i32]=na4.z; ATs[j4+3][i32]=na4.w;
        Bv[tid>>3][tid&7] = nbb;
        const int ci = tid >> 4, cj = (tid & 15) << 1;
        Cmat[ci][cj]=nc2.x; Cmat[ci][cj+1]=nc2.y;
        CT[cj][ci]=nc2.x; CT[cj+1][ci]=nc2.y;
        if (tid < PSZ) yv[tid] = nyy;
        if (tid < MSZ) uv[tid] = nuu;
      }
    }
    __syncthreads();
  }
}

// ------- Parallel smoother precompute: J_t, E_t, e_t for t=0..T-2 -------
__global__ __launch_bounds__(256) void kf_precomp(
    const float* __restrict__ Ag, float* __restrict__ outg,
    float* __restrict__ wsSig, float* __restrict__ wsMu)
{
  const int t = blockIdx.x;       // 0..126
  const int b = blockIdx.y;
  const int tid = threadIdx.x;
  const int i32 = tid >> 3;
  const int j4 = (tid & 7) << 2;
  __shared__ __align__(16) float Sf[NSZ][LD];
  __shared__ __align__(16) float AT2[NSZ][LD];
  __shared__ __align__(16) float Mm[NSZ][LD];
  __shared__ __align__(16) float Pm[NSZ][LD];
  __shared__ __align__(16) float V[NSZ][LD];
  __shared__ __align__(16) float Jl[NSZ][LD];
  __shared__ __align__(16) float JTs[NSZ][LD];
  __shared__ __align__(16) float prow[NSZ];
  __shared__ __align__(16) float vrow[NSZ];
  __shared__ float mfv[NSZ], mp1[NSZ];
  const size_t bt = (size_t)b*TT + t;
  {
    const float* os = outg + bt*NSZ*(NSZ+1);
    #pragma unroll
    for (int r = 0; r < 4; ++r) {
      int e = tid + 256*r; int i = e >> 5, j = e & 31;
      Sf[i][j] = os[i*(NSZ+1) + 1 + j];
    }
    if (tid < NSZ) mfv[tid] = os[tid*(NSZ+1)];
    float4 a4 = *(const float4*)(Ag + bt*(NSZ*NSZ) + tid*4);
    AT2[j4+0][i32]=a4.x; AT2[j4+1][i32]=a4.y; AT2[j4+2][i32]=a4.z; AT2[j4+3][i32]=a4.w;
    *(float4*)&Pm[i32][j4] = *(const float4*)(wsSig + ((bt+1)*NSZ + i32)*NSZ + j4);
    if (tid < NSZ) mp1[tid] = wsMu[(bt+1)*NSZ + tid];
    float4 vi;
    vi.x = (i32 == j4+0) ? 1.f : 0.f;
    vi.y = (i32 == j4+1) ? 1.f : 0.f;
    vi.z = (i32 == j4+2) ? 1.f : 0.f;
    vi.w = (i32 == j4+3) ? 1.f : 0.f;
    *(float4*)&V[i32][j4] = vi;
  }
  __syncthreads();
  // Mm = Sf * A^T
  {
    float4 acc = make_float4(0.f,0.f,0.f,0.f);
    #pragma unroll
    for (int k0 = 0; k0 < NSZ; k0 += 4) {
      float4 s = *(const float4*)&Sf[i32][k0];
      fma4(acc, s.x, *(const float4*)&AT2[k0+0][j4]);
      fma4(acc, s.y, *(const float4*)&AT2[k0+1][j4]);
      fma4(acc, s.z, *(const float4*)&AT2[k0+2][j4]);
      fma4(acc, s.w, *(const float4*)&AT2[k0+3][j4]);
    }
    *(float4*)&Mm[i32][j4] = acc;
  }
  __syncthreads();
  // Gauss-Jordan inversion of Pm (SPD, no pivoting) -> V
  for (int k = 0; k < NSZ; ++k) {
    float f = Pm[i32][k];
    if (tid < 8) {
      float rd = 1.0f / Pm[k][k];
      #pragma unroll
      for (int m = 0; m < 4; ++m) prow[tid*4+m] = Pm[k][tid*4+m] * rd;
    } else if (tid < 16) {
      float rd = 1.0f / Pm[k][k];
      const int c0 = (tid-8)*4;
      #pragma unroll
      for (int m = 0; m < 4; ++m) vrow[c0+m] = V[k][c0+m] * rd;
    }
    __syncthreads();
    if (i32 == k) {
      *(float4*)&Pm[k][j4] = *(const float4*)&prow[j4];
      *(float4*)&V[k][j4] = *(const float4*)&vrow[j4];
    } else {
      float4 p = *(const float4*)&Pm[i32][j4];
      float4 v = *(const float4*)&V[i32][j4];
      fma4(p, -f, *(const float4*)&prow[j4]);
      fma4(v, -f, *(const float4*)&vrow[j4]);
      *(float4*)&Pm[i32][j4] = p;
      *(float4*)&V[i32][j4] = v;
    }
    __syncthreads();
  }
  // J = Mm * V ; store J into wsSig slot (bt+1)
  {
    float4 acc = make_float4(0.f,0.f,0.f,0.f);
    #pragma unroll
    for (int k0 = 0; k0 < NSZ; k0 += 4) {
      float4 m4 = *(const float4*)&Mm[i32][k0];
      fma4(acc, m4.x, *(const float4*)&V[k0+0][j4]);
      fma4(acc, m4.y, *(const float4*)&V[k0+1][j4]);
      fma4(acc, m4.z, *(const float4*)&V[k0+2][j4]);
      fma4(acc, m4.w, *(const float4*)&V[k0+3][j4]);
    }
    *(float4*)&Jl[i32][j4] = acc;
    JTs[j4+0][i32]=acc.x; JTs[j4+1][i32]=acc.y; JTs[j4+2][i32]=acc.z; JTs[j4+3][i32]=acc.w;
    *(float4*)(wsSig + ((bt+1)*NSZ + i32)*NSZ + j4) = acc;
  }
  __syncthreads();
  // E = Sf - Mm*J^T -> out ; e = mf - J*mp1 -> out
  {
    float4 acc = make_float4(0.f,0.f,0.f,0.f);
    #pragma unroll
    for (int k0 = 0; k0 < NSZ; k0 += 4) {
      float4 m4 = *(const float4*)&Mm[i32][k0];
      fma4(acc, m4.x, *(const float4*)&JTs[k0+0][j4]);
      fma4(acc, m4.y, *(const float4*)&JTs[k0+1][j4]);
      fma4(acc, m4.z, *(const float4*)&JTs[k0+2][j4]);
      fma4(acc, m4.w, *(const float4*)&JTs[k0+3][j4]);
    }
    float* os = outg + bt*NSZ*(NSZ+1);
    os[i32*(NSZ+1)+1+j4+0] = Sf[i32][j4+0] - acc.x;
    os[i32*(NSZ+1)+1+j4+1] = Sf[i32][j4+1] - acc.y;
    os[i32*(NSZ+1)+1+j4+2] = Sf[i32][j4+2] - acc.z;
    os[i32*(NSZ+1)+1+j4+3] = Sf[i32][j4+3] - acc.w;
    if (tid < NSZ) {
      float e2 = mfv[tid];
      #pragma unroll
      for (int k = 0; k < NSZ; ++k) e2 = fmaf(-Jl[tid][k], mp1[k], e2);
      os[tid*(NSZ+1)] = e2;
    }
  }
}

// --------------- Backward smoother recursion: 1 block per batch ---------------
__global__ __launch_bounds__(256) void kf_backward(
    float* __restrict__ outg, const float* __restrict__ wsSig)
{
  const int b = blockIdx.x;
  const int tid = threadIdx.x;
  const int i32 = tid >> 3;
  const int j4 = (tid & 7) << 2;
  __shared__ __align__(16) float Sigs[NSZ][LD];
  __shared__ __align__(16) float Jl[NSZ][LD];
  __shared__ __align__(16) float JTs[NSZ][LD];
  __shared__ __align__(16) float W[NSZ][LD];
  __shared__ __align__(16) float G[NSZ][LD];
  __shared__ __align__(16) float Eb[NSZ][LD];
  __shared__ float mus[NSZ], ev[NSZ];
  const size_t base = (size_t)b*TT;
  {
    const float* os = outg + (base + TT - 1)*NSZ*(NSZ+1);
    #pragma unroll
    for (int r = 0; r < 4; ++r) {
      int e = tid + 256*r; int i = e >> 5, j = e & 31;
      Sigs[i][j] = os[i*(NSZ+1) + 1 + j];
    }
    if (tid < NSZ) mus[tid] = os[tid*(NSZ+1)];
    float4 jj = *(const float4*)(wsSig + ((base + TT - 1)*NSZ + i32)*NSZ + j4);
    *(float4*)&Jl[i32][j4] = jj;
    JTs[j4+0][i32]=jj.x; JTs[j4+1][i32]=jj.y; JTs[j4+2][i32]=jj.z; JTs[j4+3][i32]=jj.w;
    const float* oe = outg + (base + TT - 2)*NSZ*(NSZ+1);
    Eb[i32][j4+0] = oe[i32*(NSZ+1)+1+j4+0];
    Eb[i32][j4+1] = oe[i32*(NSZ+1)+1+j4+1];
    Eb[i32][j4+2] = oe[i32*(NSZ+1)+1+j4+2];
    Eb[i32][j4+3] = oe[i32*(NSZ+1)+1+j4+3];
    if (tid < NSZ) ev[tid] = oe[tid*(NSZ+1)];
  }
  __syncthreads();

  for (int t = TT - 2; t >= 0; --t) {
    // prefetch next (t-1) J / E / e
    float4 nj = make_float4(0.f,0.f,0.f,0.f);
    float ne0=0.f, ne1=0.f, ne2=0.f, ne3=0.f, nev=0.f;
    if (t > 0) {
      nj = *(const float4*)(wsSig + ((base + t)*NSZ + i32)*NSZ + j4);
      const float* oe = outg + (base + t - 1)*NSZ*(NSZ+1);
      ne0 = oe[i32*(NSZ+1)+1+j4+0];
      ne1 = oe[i32*(NSZ+1)+1+j4+1];
      ne2 = oe[i32*(NSZ+1)+1+j4+2];
      ne3 = oe[i32*(NSZ+1)+1+j4+3];
      if (tid < NSZ) nev = oe[tid*(NSZ+1)];
    }
    // W = J * Sigs
    {
      float4 acc = make_float4(0.f,0.f,0.f,0.f);
      #pragma unroll
      for (int k0 = 0; k0 < NSZ; k0 += 4) {
        float4 j4v = *(const float4*)&Jl[i32][k0];
        fma4(acc, j4v.x, *(const float4*)&Sigs[k0+0][j4]);
        fma4(acc, j4v.y, *(const float4*)&Sigs[k0+1][j4]);
        fma4(acc, j4v.z, *(const float4*)&Sigs[k0+2][j4]);
        fma4(acc, j4v.w, *(const float4*)&Sigs[k0+3][j4]);
      }
      *(float4*)&W[i32][j4] = acc;
    }
    __syncthreads();
    // G = E + W * J^T
    {
      float4 acc = make_float4(0.f,0.f,0.f,0.f);
      #pragma unroll
      for (int k0 = 0; k0 < NSZ; k0 += 4) {
        float4 w4 = *(const float4*)&W[i32][k0];
        fma4(acc, w4.x, *(const float4*)&JTs[k0+0][j4]);
        fma4(acc, w4.y, *(const float4*)&JTs[k0+1][j4]);
        fma4(acc, w4.z, *(const float4*)&JTs[k0+2][j4]);
        fma4(acc, w4.w, *(const float4*)&JTs[k0+3][j4]);
      }
      acc.x += Eb[i32][j4+0];
      acc.y += Eb[i32][j4+1];
      acc.z += Eb[i32][j4+2];
      acc.w += Eb[i32][j4+3];
      *(float4*)&G[i32][j4] = acc;
    }
    __syncthreads();
    // Signew = sym(G) ; mu update
    float4 sf;
    sf.x = 0.5f*(G[i32][j4+0] + G[j4+0][i32]);
    sf.y = 0.5f*(G[i32][j4+1] + G[j4+1][i32]);
    sf.z = 0.5f*(G[i32][j4+2] + G[j4+2][i32]);
    sf.w = 0.5f*(G[i32][j4+3] + G[j4+3][i32]);
    float mn = 0.f;
    if (tid < NSZ) {
      mn = ev[tid];
      #pragma unroll
      for (int k = 0; k < NSZ; ++k) mn = fmaf(Jl[tid][k], mus[k], mn);
    }
    __syncthreads();
    *(float4*)&Sigs[i32][j4] = sf;
    {
      float* op = outg + ((base + t)*NSZ + i32)*(NSZ+1) + 1 + j4;
      op[0]=sf.x; op[1]=sf.y; op[2]=sf.z; op[3]=sf.w;
      if (tid < NSZ) {
        mus[tid] = mn;
        outg[((base + t)*NSZ + tid)*(NSZ+1)] = mn;
      }
    }
    if (t > 0) {
      *(float4*)&Jl[i32][j4] = nj;
      JTs[j4+0][i32]=nj.x; JTs[j4+1][i32]=nj.y; JTs[j4+2][i32]=nj.z; JTs[j4+3][i32]=nj.w;
      Eb[i32][j4+0]=ne0; Eb[i32][j4+1]=ne1; Eb[i32][j4+2]=ne2; Eb[i32][j4+3]=ne3;
      if (tid < NSZ) ev[tid] = nev;
    }
    __syncthreads();
  }
}

extern "C" void kernel_launch(void* const* d_in, const int* in_sizes, int n_in,
                              void* d_out, int out_size, void* d_ws, size_t ws_size,
                              hipStream_t stream) {
  (void)in_sizes; (void)n_in; (void)out_size; (void)ws_size;
  const float* Yg   = (const float*)d_in[0];
  const float* Ug   = (const float*)d_in[1];
  const float* Ag   = (const float*)d_in[2];
  const float* Bg   = (const float*)d_in[3];
  const float* Cg   = (const float*)d_in[4];
  const float* mu0g = (const float*)d_in[5];
  const float* S0g  = (const float*)d_in[6];
  float* outg = (float*)d_out;
  float* wsSig = (float*)d_ws;                              // B*T*N*N floats
  float* wsMu  = wsSig + (size_t)NB*TT*NSZ*NSZ;             // B*T*N floats

  hipLaunchKernelGGL(kf_forward, dim3(NB), dim3(256), 0, stream,
                     Yg, Ug, Ag, Bg, Cg, mu0g, S0g, outg, wsSig, wsMu);
  hipLaunchKernelGGL(kf_precomp, dim3(TT-1, NB), dim3(256), 0, stream,
                     Ag, outg, wsSig, wsMu);
  hipLaunchKernelGGL(kf_backward, dim3(NB), dim3(256), 0, stream,
                     outg, wsSig);
}

// Round 2
// 1415.268 us; speedup vs baseline: 1.2331x; 1.2331x over previous
//
#include <hip/hip_runtime.h>

#define TT 128
#define NB 64
#define NSZ 32
#define MSZ 8
#define PSZ 16
#define LD 36
#define LDC 20

__device__ __forceinline__ void fma4(float4& a, float s, const float4 v){
  a.x = fmaf(s, v.x, a.x);
  a.y = fmaf(s, v.y, a.y);
  a.z = fmaf(s, v.z, a.z);
  a.w = fmaf(s, v.w, a.w);
}
__device__ __forceinline__ void fma2(float2& a, float s, const float2 v){
  a.x = fmaf(s, v.x, a.x);
  a.y = fmaf(s, v.y, a.y);
}
// Barrier that drains ONLY LDS ops (lgkmcnt). vmcnt stays counted so the
// per-step global prefetch loads + output stores remain in flight across
// barriers (T4: never drain vmcnt in the main loop).
__device__ __forceinline__ void bar(){
  asm volatile("s_waitcnt lgkmcnt(0)" ::: "memory");
  __builtin_amdgcn_s_barrier();
  asm volatile("" ::: "memory");
}
__device__ __forceinline__ float frcp(float x){ return __builtin_amdgcn_rcpf(x); }
__device__ __forceinline__ float frsq(float x){ return __builtin_amdgcn_rsqf(x); }

// ---------------- Forward Kalman filter: 1 block per batch ----------------
__global__ __launch_bounds__(256) void kf_forward(
    const float* __restrict__ Yg, const float* __restrict__ Ug,
    const float* __restrict__ Ag, const float* __restrict__ Bg,
    const float* __restrict__ Cg, const float* __restrict__ mu0g,
    const float* __restrict__ Sig0g,
    float* __restrict__ outg, float* __restrict__ wsSig, float* __restrict__ wsMu)
{
  const int b = blockIdx.x;
  const int tid = threadIdx.x;
  const int i32 = tid >> 3;
  const int j4 = (tid & 7) << 2;
  const int i16 = tid >> 4;
  const int j2 = (tid & 15) << 1;
  const int sj = tid & 15;

  __shared__ __align__(16) float Sig[NSZ][LD];
  __shared__ __align__(16) float Amat[NSZ][LD];
  __shared__ __align__(16) float ATs[NSZ][LD];
  __shared__ __align__(16) float T1[NSZ][LD];
  __shared__ __align__(16) float Sigp[NSZ][LD];
  __shared__ __align__(16) float Cmat[PSZ][LD];
  __shared__ __align__(16) float CS[PSZ][LD];
  __shared__ __align__(16) float Kt[PSZ][LD];
  __shared__ __align__(16) float CT[NSZ][LDC];
  __shared__ float Lch[PSZ][17];
  __shared__ float Sraw[PSZ][17];
  __shared__ float rdiag[PSZ];
  __shared__ float Bv[NSZ][9];
  __shared__ float yv[PSZ], uv[MSZ], muv[NSZ], mupv[NSZ], rvv[PSZ], mufv[NSZ];

  const size_t bt0 = (size_t)b * TT;

  for (int e = tid; e < NSZ*NSZ; e += 256) Sig[e >> 5][e & 31] = Sig0g[e];
  if (tid < NSZ) muv[tid] = mu0g[tid];
  {
    float4 a4 = *(const float4*)(Ag + bt0*(NSZ*NSZ) + tid*4);
    float bb = Bg[bt0*(NSZ*MSZ) + tid];
    float2 c2 = *(const float2*)(Cg + bt0*(PSZ*NSZ) + tid*2);
    Amat[i32][j4+0]=a4.x; Amat[i32][j4+1]=a4.y; Amat[i32][j4+2]=a4.z; Amat[i32][j4+3]=a4.w;
    ATs[j4+0][i32]=a4.x; ATs[j4+1][i32]=a4.y; ATs[j4+2][i32]=a4.z; ATs[j4+3][i32]=a4.w;
    Bv[tid>>3][tid&7] = bb;
    const int ci = tid >> 4, cj = (tid & 15) << 1;
    Cmat[ci][cj]=c2.x; Cmat[ci][cj+1]=c2.y;
    CT[cj][ci]=c2.x; CT[cj+1][ci]=c2.y;
    if (tid < PSZ) yv[tid] = Yg[bt0*PSZ + tid];
    if (tid < MSZ) uv[tid] = Ug[bt0*MSZ + tid];
  }
  __syncthreads();

  for (int t = 0; t < TT; ++t) {
    const size_t bt = bt0 + t;
    // prefetch next step's inputs into registers (stay in flight across bar()s)
    float4 na4 = make_float4(0.f,0.f,0.f,0.f);
    float2 nc2 = make_float2(0.f,0.f);
    float nbb = 0.f, nyy = 0.f, nuu = 0.f;
    if (t + 1 < TT) {
      na4 = *(const float4*)(Ag + (bt+1)*(NSZ*NSZ) + tid*4);
      nbb = Bg[(bt+1)*(NSZ*MSZ) + tid];
      nc2 = *(const float2*)(Cg + (bt+1)*(PSZ*NSZ) + tid*2);
      if (tid < PSZ) nyy = Yg[(bt+1)*PSZ + tid];
      if (tid < MSZ) nuu = Ug[(bt+1)*MSZ + tid];
    }

    // Phase A: T1 = A*Sig ; mu_p = A*mu + B*u
    {
      float4 acc = make_float4(0.f,0.f,0.f,0.f);
      #pragma unroll
      for (int k0 = 0; k0 < NSZ; k0 += 4) {
        float4 a = *(const float4*)&Amat[i32][k0];
        fma4(acc, a.x, *(const float4*)&Sig[k0+0][j4]);
        fma4(acc, a.y, *(const float4*)&Sig[k0+1][j4]);
        fma4(acc, a.z, *(const float4*)&Sig[k0+2][j4]);
        fma4(acc, a.w, *(const float4*)&Sig[k0+3][j4]);
      }
      *(float4*)&T1[i32][j4] = acc;
      if (tid < NSZ) {
        float m = 0.f;
        #pragma unroll
        for (int k = 0; k < NSZ; ++k) m = fmaf(ATs[k][tid], muv[k], m);
        #pragma unroll
        for (int k = 0; k < MSZ; ++k) m = fmaf(Bv[tid][k], uv[k], m);
        mupv[tid] = m;
      }
    }
    bar();

    // Phase B: Sig_p = T1*A^T + Q ; store Sig_p, mu_p to workspace
    {
      float4 acc = make_float4(0.f,0.f,0.f,0.f);
      #pragma unroll
      for (int k0 = 0; k0 < NSZ; k0 += 4) {
        float4 a = *(const float4*)&T1[i32][k0];
        fma4(acc, a.x, *(const float4*)&ATs[k0+0][j4]);
        fma4(acc, a.y, *(const float4*)&ATs[k0+1][j4]);
        fma4(acc, a.z, *(const float4*)&ATs[k0+2][j4]);
        fma4(acc, a.w, *(const float4*)&ATs[k0+3][j4]);
      }
      acc.x += (i32 == j4+0) ? 0.01f : 0.f;
      acc.y += (i32 == j4+1) ? 0.01f : 0.f;
      acc.z += (i32 == j4+2) ? 0.01f : 0.f;
      acc.w += (i32 == j4+3) ? 0.01f : 0.f;
      *(float4*)&Sigp[i32][j4] = acc;
      *(float4*)(wsSig + (bt*NSZ + i32)*NSZ + j4) = acc;
      if (tid < NSZ) wsMu[bt*NSZ + tid] = mupv[tid];
    }
    bar();

    // Phase C: CS = C*Sig_p (16x32) ; r = y - C*mu_p
    {
      float2 acc = make_float2(0.f,0.f);
      #pragma unroll
      for (int k0 = 0; k0 < NSZ; k0 += 4) {
        float4 c4 = *(const float4*)&Cmat[i16][k0];
        fma2(acc, c4.x, *(const float2*)&Sigp[k0+0][j2]);
        fma2(acc, c4.y, *(const float2*)&Sigp[k0+1][j2]);
        fma2(acc, c4.z, *(const float2*)&Sigp[k0+2][j2]);
        fma2(acc, c4.w, *(const float2*)&Sigp[k0+3][j2]);
      }
      *(float2*)&CS[i16][j2] = acc;
      if (tid < PSZ) {
        float r = yv[tid];
        #pragma unroll
        for (int k = 0; k < NSZ; ++k) r = fmaf(-CT[k][tid], mupv[k], r);
        rvv[tid] = r;
      }
    }
    bar();

    // Phase D: Sraw = CS*C^T + R (16x16)
    {
      float acc = 0.f;
      #pragma unroll
      for (int k0 = 0; k0 < NSZ; k0 += 4) {
        float4 cs4 = *(const float4*)&CS[i16][k0];
        acc = fmaf(cs4.x, CT[k0+0][sj], acc);
        acc = fmaf(cs4.y, CT[k0+1][sj], acc);
        acc = fmaf(cs4.z, CT[k0+2][sj], acc);
        acc = fmaf(cs4.w, CT[k0+3][sj], acc);
      }
      Sraw[i16][sj] = acc + ((i16 == sj) ? 0.01f : 0.f);
    }
    bar();

    // Phase EG: wave 0 only — Cholesky of sym(Sraw) then solve S*Kt = CS
    if (tid < 64) {
      const int j = tid & 15;
      float col[16];
      #pragma unroll
      for (int i = 0; i < 16; ++i) col[i] = 0.5f*(Sraw[i][j] + Sraw[j][i]);
      #pragma unroll
      for (int k = 0; k < 16; ++k) {
        float ck[16];
        #pragma unroll
        for (int i = 0; i < 16; ++i) { if (i >= k) ck[i] = __shfl(col[i], k); else ck[i] = 0.f; }
        float rd = frsq(ck[k]);
        if (j == k) {
          #pragma unroll
          for (int i = 0; i < 16; ++i) { if (i >= k) col[i] = ck[i]*rd; }
        } else if (j > k) {
          float ljk = ck[j]*rd;
          #pragma unroll
          for (int i = 0; i < 16; ++i) { if (i > k) col[i] = fmaf(-(ck[i]*rd), ljk, col[i]); }
        }
      }
      if (tid < 16) {
        #pragma unroll
        for (int i = 0; i < 16; ++i) { if (i >= j) Lch[i][j] = col[i]; }
        rdiag[j] = frcp(col[j]);
      }
    }
    // wave-synchronous continuation in wave 0 (same-wave LDS is in-order)
    if (tid < 32) {
      float x[16];
      #pragma unroll
      for (int i = 0; i < 16; ++i) x[i] = CS[i][tid];
      #pragma unroll
      for (int i = 0; i < 16; ++i) {          // L y = c (column-oriented)
        x[i] *= rdiag[i];
        #pragma unroll
        for (int m = 0; m < 16; ++m) { if (m > i) x[m] = fmaf(-Lch[m][i], x[i], x[m]); }
      }
      #pragma unroll
      for (int i = 15; i >= 0; --i) {         // L^T z = y (column-oriented)
        x[i] *= rdiag[i];
        #pragma unroll
        for (int m = 0; m < 16; ++m) { if (m < i) x[m] = fmaf(-Lch[i][m], x[i], x[m]); }
        Kt[i][tid] = x[i];
      }
    }
    bar();

    // Phase H: T1 = Sig_p - K*CS (standard form) ; mu_f = mu_p + K*r
    {
      float4 acc = *(const float4*)&Sigp[i32][j4];
      #pragma unroll
      for (int p = 0; p < PSZ; ++p) {
        float kv = Kt[p][i32];
        fma4(acc, -kv, *(const float4*)&CS[p][j4]);
      }
      *(float4*)&T1[i32][j4] = acc;
      if (tid < NSZ) {
        float m = mupv[tid];
        #pragma unroll
        for (int p = 0; p < PSZ; ++p) m = fmaf(Kt[p][tid], rvv[p], m);
        mufv[tid] = m;
      }
    }
    bar();

    // Phase K: Sig_f = sym(T1) ; outputs ; stage next inputs
    {
      float4 sf;
      sf.x = 0.5f*(T1[i32][j4+0] + T1[j4+0][i32]);
      sf.y = 0.5f*(T1[i32][j4+1] + T1[j4+1][i32]);
      sf.z = 0.5f*(T1[i32][j4+2] + T1[j4+2][i32]);
      sf.w = 0.5f*(T1[i32][j4+3] + T1[j4+3][i32]);
      *(float4*)&Sig[i32][j4] = sf;
      float* op = outg + (bt*NSZ + i32)*(NSZ+1) + 1 + j4;
      op[0]=sf.x; op[1]=sf.y; op[2]=sf.z; op[3]=sf.w;
      if (tid < NSZ) {
        muv[tid] = mufv[tid];
        outg[(bt*NSZ + tid)*(NSZ+1)] = mufv[tid];
      }
      if (t + 1 < TT) {
        Amat[i32][j4+0]=na4.x; Amat[i32][j4+1]=na4.y; Amat[i32][j4+2]=na4.z; Amat[i32][j4+3]=na4.w;
        ATs[j4+0][i32]=na4.x; ATs[j4+1][i32]=na4.y; ATs[j4+2][i32]=na4.z; ATs[j4+3][i32]=na4.w;
        Bv[tid>>3][tid&7] = nbb;
        const int ci = tid >> 4, cj = (tid & 15) << 1;
        Cmat[ci][cj]=nc2.x; Cmat[ci][cj+1]=nc2.y;
        CT[cj][ci]=nc2.x; CT[cj+1][ci]=nc2.y;
        if (tid < PSZ) yv[tid] = nyy;
        if (tid < MSZ) uv[tid] = nuu;
      }
    }
    bar();
  }
}

// ------- Parallel smoother precompute: J_t, E_t, e_t for t=0..T-2 -------
__global__ __launch_bounds__(256) void kf_precomp(
    const float* __restrict__ Ag, float* __restrict__ outg,
    float* __restrict__ wsSig, float* __restrict__ wsMu)
{
  const int t = blockIdx.x;       // 0..126
  const int b = blockIdx.y;
  const int tid = threadIdx.x;
  const int i32 = tid >> 3;
  const int j4 = (tid & 7) << 2;
  __shared__ __align__(16) float Sf[NSZ][LD];
  __shared__ __align__(16) float AT2[NSZ][LD];
  __shared__ __align__(16) float Mm[NSZ][LD];
  __shared__ __align__(16) float Pm[NSZ][LD];
  __shared__ __align__(16) float V[NSZ][LD];
  __shared__ __align__(16) float Jl[NSZ][LD];
  __shared__ __align__(16) float JTs[NSZ][LD];
  __shared__ __align__(16) float prow[NSZ];
  __shared__ __align__(16) float vrow[NSZ];
  __shared__ float mfv[NSZ], mp1[NSZ];
  const size_t bt = (size_t)b*TT + t;
  {
    const float* os = outg + bt*NSZ*(NSZ+1);
    #pragma unroll
    for (int r = 0; r < 4; ++r) {
      int e = tid + 256*r; int i = e >> 5, j = e & 31;
      Sf[i][j] = os[i*(NSZ+1) + 1 + j];
    }
    if (tid < NSZ) mfv[tid] = os[tid*(NSZ+1)];
    float4 a4 = *(const float4*)(Ag + bt*(NSZ*NSZ) + tid*4);
    AT2[j4+0][i32]=a4.x; AT2[j4+1][i32]=a4.y; AT2[j4+2][i32]=a4.z; AT2[j4+3][i32]=a4.w;
    *(float4*)&Pm[i32][j4] = *(const float4*)(wsSig + ((bt+1)*NSZ + i32)*NSZ + j4);
    if (tid < NSZ) mp1[tid] = wsMu[(bt+1)*NSZ + tid];
    float4 vi;
    vi.x = (i32 == j4+0) ? 1.f : 0.f;
    vi.y = (i32 == j4+1) ? 1.f : 0.f;
    vi.z = (i32 == j4+2) ? 1.f : 0.f;
    vi.w = (i32 == j4+3) ? 1.f : 0.f;
    *(float4*)&V[i32][j4] = vi;
  }
  __syncthreads();
  // Mm = Sf * A^T
  {
    float4 acc = make_float4(0.f,0.f,0.f,0.f);
    #pragma unroll
    for (int k0 = 0; k0 < NSZ; k0 += 4) {
      float4 s = *(const float4*)&Sf[i32][k0];
      fma4(acc, s.x, *(const float4*)&AT2[k0+0][j4]);
      fma4(acc, s.y, *(const float4*)&AT2[k0+1][j4]);
      fma4(acc, s.z, *(const float4*)&AT2[k0+2][j4]);
      fma4(acc, s.w, *(const float4*)&AT2[k0+3][j4]);
    }
    *(float4*)&Mm[i32][j4] = acc;
  }
  __syncthreads();
  // Gauss-Jordan inversion of Pm (SPD, no pivoting) -> V
  for (int k = 0; k < NSZ; ++k) {
    float f = Pm[i32][k];
    if (tid < 8) {
      float rd = frcp(Pm[k][k]);
      #pragma unroll
      for (int m = 0; m < 4; ++m) prow[tid*4+m] = Pm[k][tid*4+m] * rd;
    } else if (tid < 16) {
      float rd = frcp(Pm[k][k]);
      const int c0 = (tid-8)*4;
      #pragma unroll
      for (int m = 0; m < 4; ++m) vrow[c0+m] = V[k][c0+m] * rd;
    }
    __syncthreads();
    if (i32 == k) {
      *(float4*)&Pm[k][j4] = *(const float4*)&prow[j4];
      *(float4*)&V[k][j4] = *(const float4*)&vrow[j4];
    } else {
      float4 p = *(const float4*)&Pm[i32][j4];
      float4 v = *(const float4*)&V[i32][j4];
      fma4(p, -f, *(const float4*)&prow[j4]);
      fma4(v, -f, *(const float4*)&vrow[j4]);
      *(float4*)&Pm[i32][j4] = p;
      *(float4*)&V[i32][j4] = v;
    }
    __syncthreads();
  }
  // J = Mm * V ; store J into wsSig slot (bt+1)
  {
    float4 acc = make_float4(0.f,0.f,0.f,0.f);
    #pragma unroll
    for (int k0 = 0; k0 < NSZ; k0 += 4) {
      float4 m4 = *(const float4*)&Mm[i32][k0];
      fma4(acc, m4.x, *(const float4*)&V[k0+0][j4]);
      fma4(acc, m4.y, *(const float4*)&V[k0+1][j4]);
      fma4(acc, m4.z, *(const float4*)&V[k0+2][j4]);
      fma4(acc, m4.w, *(const float4*)&V[k0+3][j4]);
    }
    *(float4*)&Jl[i32][j4] = acc;
    JTs[j4+0][i32]=acc.x; JTs[j4+1][i32]=acc.y; JTs[j4+2][i32]=acc.z; JTs[j4+3][i32]=acc.w;
    *(float4*)(wsSig + ((bt+1)*NSZ + i32)*NSZ + j4) = acc;
  }
  __syncthreads();
  // E = Sf - Mm*J^T -> out ; e = mf - J*mp1 -> out
  {
    float4 acc = make_float4(0.f,0.f,0.f,0.f);
    #pragma unroll
    for (int k0 = 0; k0 < NSZ; k0 += 4) {
      float4 m4 = *(const float4*)&Mm[i32][k0];
      fma4(acc, m4.x, *(const float4*)&JTs[k0+0][j4]);
      fma4(acc, m4.y, *(const float4*)&JTs[k0+1][j4]);
      fma4(acc, m4.z, *(const float4*)&JTs[k0+2][j4]);
      fma4(acc, m4.w, *(const float4*)&JTs[k0+3][j4]);
    }
    float* os = outg + bt*NSZ*(NSZ+1);
    os[i32*(NSZ+1)+1+j4+0] = Sf[i32][j4+0] - acc.x;
    os[i32*(NSZ+1)+1+j4+1] = Sf[i32][j4+1] - acc.y;
    os[i32*(NSZ+1)+1+j4+2] = Sf[i32][j4+2] - acc.z;
    os[i32*(NSZ+1)+1+j4+3] = Sf[i32][j4+3] - acc.w;
    if (tid < NSZ) {
      float e2 = mfv[tid];
      #pragma unroll
      for (int k = 0; k < NSZ; ++k) e2 = fmaf(-Jl[tid][k], mp1[k], e2);
      os[tid*(NSZ+1)] = e2;
    }
  }
}

// --------------- Backward smoother recursion: 1 block per batch ---------------
__global__ __launch_bounds__(256) void kf_backward(
    float* __restrict__ outg, const float* __restrict__ wsSig)
{
  const int b = blockIdx.x;
  const int tid = threadIdx.x;
  const int i32 = tid >> 3;
  const int j4 = (tid & 7) << 2;
  __shared__ __align__(16) float Sigs[NSZ][LD];
  __shared__ __align__(16) float Jl[NSZ][LD];
  __shared__ __align__(16) float JTs[NSZ][LD];
  __shared__ __align__(16) float W[NSZ][LD];
  __shared__ __align__(16) float G[NSZ][LD];
  __shared__ __align__(16) float Eb[NSZ][LD];
  __shared__ float mus[NSZ], ev[NSZ];
  const size_t base = (size_t)b*TT;
  {
    const float* os = outg + (base + TT - 1)*NSZ*(NSZ+1);
    #pragma unroll
    for (int r = 0; r < 4; ++r) {
      int e = tid + 256*r; int i = e >> 5, j = e & 31;
      Sigs[i][j] = os[i*(NSZ+1) + 1 + j];
    }
    if (tid < NSZ) mus[tid] = os[tid*(NSZ+1)];
    float4 jj = *(const float4*)(wsSig + ((base + TT - 1)*NSZ + i32)*NSZ + j4);
    *(float4*)&Jl[i32][j4] = jj;
    JTs[j4+0][i32]=jj.x; JTs[j4+1][i32]=jj.y; JTs[j4+2][i32]=jj.z; JTs[j4+3][i32]=jj.w;
    const float* oe = outg + (base + TT - 2)*NSZ*(NSZ+1);
    Eb[i32][j4+0] = oe[i32*(NSZ+1)+1+j4+0];
    Eb[i32][j4+1] = oe[i32*(NSZ+1)+1+j4+1];
    Eb[i32][j4+2] = oe[i32*(NSZ+1)+1+j4+2];
    Eb[i32][j4+3] = oe[i32*(NSZ+1)+1+j4+3];
    if (tid < NSZ) ev[tid] = oe[tid*(NSZ+1)];
  }
  __syncthreads();

  for (int t = TT - 2; t >= 0; --t) {
    // prefetch next (t-1) J / E / e — stay in flight across bar()s
    float4 nj = make_float4(0.f,0.f,0.f,0.f);
    float ne0=0.f, ne1=0.f, ne2=0.f, ne3=0.f, nev=0.f;
    if (t > 0) {
      nj = *(const float4*)(wsSig + ((base + t)*NSZ + i32)*NSZ + j4);
      const float* oe = outg + (base + t - 1)*NSZ*(NSZ+1);
      ne0 = oe[i32*(NSZ+1)+1+j4+0];
      ne1 = oe[i32*(NSZ+1)+1+j4+1];
      ne2 = oe[i32*(NSZ+1)+1+j4+2];
      ne3 = oe[i32*(NSZ+1)+1+j4+3];
      if (tid < NSZ) nev = oe[tid*(NSZ+1)];
    }
    // W = J * Sigs
    {
      float4 acc = make_float4(0.f,0.f,0.f,0.f);
      #pragma unroll
      for (int k0 = 0; k0 < NSZ; k0 += 4) {
        float4 j4v = *(const float4*)&Jl[i32][k0];
        fma4(acc, j4v.x, *(const float4*)&Sigs[k0+0][j4]);
        fma4(acc, j4v.y, *(const float4*)&Sigs[k0+1][j4]);
        fma4(acc, j4v.z, *(const float4*)&Sigs[k0+2][j4]);
        fma4(acc, j4v.w, *(const float4*)&Sigs[k0+3][j4]);
      }
      *(float4*)&W[i32][j4] = acc;
    }
    bar();
    // G = E + W * J^T
    {
      float4 acc = make_float4(0.f,0.f,0.f,0.f);
      #pragma unroll
      for (int k0 = 0; k0 < NSZ; k0 += 4) {
        float4 w4 = *(const float4*)&W[i32][k0];
        fma4(acc, w4.x, *(const float4*)&JTs[k0+0][j4]);
        fma4(acc, w4.y, *(const float4*)&JTs[k0+1][j4]);
        fma4(acc, w4.z, *(const float4*)&JTs[k0+2][j4]);
        fma4(acc, w4.w, *(const float4*)&JTs[k0+3][j4]);
      }
      acc.x += Eb[i32][j4+0];
      acc.y += Eb[i32][j4+1];
      acc.z += Eb[i32][j4+2];
      acc.w += Eb[i32][j4+3];
      *(float4*)&G[i32][j4] = acc;
    }
    bar();
    // Signew = sym(G) ; mu update
    float4 sf;
    sf.x = 0.5f*(G[i32][j4+0] + G[j4+0][i32]);
    sf.y = 0.5f*(G[i32][j4+1] + G[j4+1][i32]);
    sf.z = 0.5f*(G[i32][j4+2] + G[j4+2][i32]);
    sf.w = 0.5f*(G[i32][j4+3] + G[j4+3][i32]);
    float mn = 0.f;
    if (tid < NSZ) {
      mn = ev[tid];
      #pragma unroll
      for (int k = 0; k < NSZ; ++k) mn = fmaf(Jl[tid][k], mus[k], mn);
    }
    bar();
    *(float4*)&Sigs[i32][j4] = sf;
    {
      float* op = outg + ((base + t)*NSZ + i32)*(NSZ+1) + 1 + j4;
      op[0]=sf.x; op[1]=sf.y; op[2]=sf.z; op[3]=sf.w;
      if (tid < NSZ) {
        mus[tid] = mn;
        outg[((base + t)*NSZ + tid)*(NSZ+1)] = mn;
      }
    }
    if (t > 0) {
      *(float4*)&Jl[i32][j4] = nj;
      JTs[j4+0][i32]=nj.x; JTs[j4+1][i32]=nj.y; JTs[j4+2][i32]=nj.z; JTs[j4+3][i32]=nj.w;
      Eb[i32][j4+0]=ne0; Eb[i32][j4+1]=ne1; Eb[i32][j4+2]=ne2; Eb[i32][j4+3]=ne3;
      if (tid < NSZ) ev[tid] = nev;
    }
    bar();
  }
}

extern "C" void kernel_launch(void* const* d_in, const int* in_sizes, int n_in,
                              void* d_out, int out_size, void* d_ws, size_t ws_size,
                              hipStream_t stream) {
  (void)in_sizes; (void)n_in; (void)out_size; (void)ws_size;
  const float* Yg   = (const float*)d_in[0];
  const float* Ug   = (const float*)d_in[1];
  const float* Ag   = (const float*)d_in[2];
  const float* Bg   = (const float*)d_in[3];
  const float* Cg   = (const float*)d_in[4];
  const float* mu0g = (const float*)d_in[5];
  const float* S0g  = (const float*)d_in[6];
  float* outg = (float*)d_out;
  float* wsSig = (float*)d_ws;                              // B*T*N*N floats
  float* wsMu  = wsSig + (size_t)NB*TT*NSZ*NSZ;             // B*T*N floats

  hipLaunchKernelGGL(kf_forward, dim3(NB), dim3(256), 0, stream,
                     Yg, Ug, Ag, Bg, Cg, mu0g, S0g, outg, wsSig, wsMu);
  hipLaunchKernelGGL(kf_precomp, dim3(TT-1, NB), dim3(256), 0, stream,
                     Ag, outg, wsSig, wsMu);
  hipLaunchKernelGGL(kf_backward, dim3(NB), dim3(256), 0, stream,
                     outg, wsSig);
}